// Round 7
// baseline (287.523 us; speedup 1.0000x reference)
//
#include <hip/hip_runtime.h>
#include <hip/hip_fp16.h>

// DGCNN forward, fully fused: one workgroup per graph, target 2 blocks/CU.
// f32 everywhere on the sort-key-critical chain; h1/h2 archived to global
// scratch as f16 (conv features only); h3 read back from LDS in f32.
//
// Occupancy discipline (hard-won over R3-R6):
//  * NO launch_bounds min-waves / waves_per_eu hints: they pin the allocator
//    at 32 VGPR with ~200 MB/launch scratch-spill traffic (R3/R4/R5).
//  * SGPR matters: 20 kernarg pointers -> SGPR_Count 96 -> 112-granule alloc
//    -> 7 waves/EU -> a second 16-wave block cannot co-schedule (R6: 45% occ).
//    Weights are pre-packed into d_ws by a tiny kernel so the main kernel
//    takes 5 pointers only.

#define TPB   1024
#define GRID  512
#define MG    200
#define EPG   6400
#define EE    (512 * EPG)

// ---- LDS layout (byte offsets). Total 78,336 B -> 2 blocks/CU (156.7/160 KiB) ----
#define OFF_BUFX 0        // f32[201*36] rows 0..200 (row 200 = zeros); later topv[30][100] + conv W
#define OFF_HCUR 28944    // f32[200*36] current-layer h (f32); later conv scratch
#define OFF_CSR  57744    // u8[7200]    CSR (rows padded to x4 entries, pad -> 200)
#define OFF_ROFF 64944    // i32[201] row offsets (padded units)
#define OFF_CNT  65760    // i32[200] degree counts   \ scl f32[201] aliases CNT..CUR
#define OFF_CUR  66560    // i32[200] cursors         /
#define OFF_DINV 67360    // f32[200]
#define OFF_H4   68160    // f32[200] sort key
#define OFF_RANK 68960    // i32[200]
#define OFF_ORD  69760    // i32[30]
#define OFF_BIAS 69880    // f32[48]
#define OFF_RED  70072    // f32[16] (+8 pad)
#define OFF_WREG 70144    // f32[2048] current weight stage (W1 in 8KB halves)
#define SMEM_BYTES 78336

// ---- packed-weights float offsets inside d_ws (after the 13.1 MB arch region) ----
#define ARCH_BYTES 13107200   // 512*200*64*2
#define PW_W1   0
#define PW_B1   4096
#define PW_W2   4128
#define PW_B2   5152
#define PW_W3   5184
#define PW_B3   6208
#define PW_W4   6240
#define PW_B4   6272
#define PW_CW1  6273
#define PW_CB1  7825
#define PW_CW2  7841
#define PW_CB2  10401
#define PW_LW1  10433
#define PW_LB1  55489
#define PW_LW2  55617
#define PW_LB2  55745
#define PW_TOTAL 55746

__global__ __launch_bounds__(256) void pack_weights(
    const float* __restrict__ W1, const float* __restrict__ b1,
    const float* __restrict__ W2, const float* __restrict__ b2,
    const float* __restrict__ W3, const float* __restrict__ b3,
    const float* __restrict__ W4, const float* __restrict__ b4,
    const float* __restrict__ cW1, const float* __restrict__ cb1,
    const float* __restrict__ cW2, const float* __restrict__ cb2,
    const float* __restrict__ lW1, const float* __restrict__ lb1,
    const float* __restrict__ lW2, const float* __restrict__ lb2,
    float* __restrict__ wp)
{
    const int t  = blockIdx.x * 256 + threadIdx.x;
    const int st = gridDim.x * 256;
    for (int i = t; i < 4096;  i += st) wp[PW_W1  + i] = W1[i];
    for (int i = t; i < 32;    i += st) wp[PW_B1  + i] = b1[i];
    for (int i = t; i < 1024;  i += st) wp[PW_W2  + i] = W2[i];
    for (int i = t; i < 32;    i += st) wp[PW_B2  + i] = b2[i];
    for (int i = t; i < 1024;  i += st) wp[PW_W3  + i] = W3[i];
    for (int i = t; i < 32;    i += st) wp[PW_B3  + i] = b3[i];
    for (int i = t; i < 32;    i += st) wp[PW_W4  + i] = W4[i];
    for (int i = t; i < 1;     i += st) wp[PW_B4  + i] = b4[i];
    for (int i = t; i < 1552;  i += st) wp[PW_CW1 + i] = cW1[i];
    for (int i = t; i < 16;    i += st) wp[PW_CB1 + i] = cb1[i];
    for (int i = t; i < 2560;  i += st) wp[PW_CW2 + i] = cW2[i];
    for (int i = t; i < 32;    i += st) wp[PW_CB2 + i] = cb2[i];
    for (int i = t; i < 45056; i += st) wp[PW_LW1 + i] = lW1[i];
    for (int i = t; i < 128;   i += st) wp[PW_LB1 + i] = lb1[i];
    for (int i = t; i < 128;   i += st) wp[PW_LW2 + i] = lW2[i];
    for (int i = t; i < 1;     i += st) wp[PW_LB2 + i] = lb2[i];
}

__global__ __launch_bounds__(TPB)
void dgcnn_kernel(
    const float* __restrict__ x,
    const int*   __restrict__ ei,
    const float* __restrict__ wp,   // packed weights (see PW_* offsets)
    __half* __restrict__ arch,      // [512][200][64] f16 archive of h1|h2
    float* __restrict__ out)
{
    extern __shared__ unsigned char smem[];
    float* bufX = (float*)(smem + OFF_BUFX);
    float* hcur = (float*)(smem + OFF_HCUR);
    unsigned char* csr = (unsigned char*)(smem + OFF_CSR);
    int*   roff = (int*)(smem + OFF_ROFF);
    int*   cnt  = (int*)(smem + OFF_CNT);
    int*   cur  = (int*)(smem + OFF_CUR);
    float* dinv = (float*)(smem + OFF_DINV);
    float* h4k  = (float*)(smem + OFF_H4);
    int*   rank = (int*)(smem + OFF_RANK);
    int*   ord  = (int*)(smem + OFF_ORD);
    float* bias = (float*)(smem + OFF_BIAS);
    float* red  = (float*)(smem + OFF_RED);
    float* wreg = (float*)(smem + OFF_WREG);

    const float* W1  = wp + PW_W1;
    const float* b1  = wp + PW_B1;
    const float* W2  = wp + PW_W2;
    const float* b2  = wp + PW_B2;
    const float* W3  = wp + PW_W3;
    const float* b3  = wp + PW_B3;
    const float* W4  = wp + PW_W4;
    const float* b4  = wp + PW_B4;
    const float* cW1 = wp + PW_CW1;
    const float* cb1 = wp + PW_CB1;
    const float* cW2 = wp + PW_CW2;
    const float* cb2 = wp + PW_CB2;
    const float* lW1 = wp + PW_LW1;
    const float* lb1 = wp + PW_LB1;
    const float* lW2 = wp + PW_LW2;
    const float* lb2 = wp + PW_LB2;

    const int g = blockIdx.x;
    const int t = threadIdx.x;
    const int gbase = g * MG;
    const float* xg   = x + (size_t)gbase * 128;
    const int*   srcp = ei + (size_t)g * EPG;
    const int*   dstp = ei + (size_t)EE + (size_t)g * EPG;

    // ---------------- Phase A: stage W1 half 1, zero counters + zero row ----------------
    for (int idx = t; idx < 2048; idx += TPB) wreg[idx] = W1[idx];
    if (t < 32) bias[t] = b1[t];
    if (t < MG) { cnt[t] = 0; rank[t] = 0; }
    if (t >= 512 && t < 548) bufX[200 * 36 + (t - 512)] = 0.f;   // zero row 200
    __syncthreads();

    // ---------------- Phase B: in-degree count ----------------
    for (int e = t; e < EPG; e += TPB) atomicAdd(&cnt[dstp[e] - gbase], 1);
    __syncthreads();

    // ---------------- Phase C: dinv + prefix scan over PADDED row lengths ----------------
    if (t >= 256 && t < 256 + MG) {
        int i = t - 256;
        dinv[i] = 1.0f / sqrtf((float)(cnt[i] + 1));
    }
    if (t < 64) {
        if (t == 0) roff[0] = 0;
        int carry = 0;
        #pragma unroll
        for (int c = 0; c < 4; ++c) {
            const int i = c * 64 + t;
            int v = (i < MG) ? ((cnt[i] + 4) & ~3) : 0;   // self-loop +1, pad to x4
            #pragma unroll
            for (int off = 1; off < 64; off <<= 1) {
                int u = __shfl_up(v, off);
                if (t >= (int)off) v += u;
            }
            if (i < MG) roff[i + 1] = carry + v;
            carry += __shfl(v, 63);
        }
    }
    __syncthreads();

    // ---------------- Phase D: self-loop entry + cursors ----------------
    if (t < MG) {
        int p = roff[t];
        csr[p] = (unsigned char)t;
        cur[t] = p + 1;
    }
    __syncthreads();

    // ---------------- Phase E: CSR placement ----------------
    for (int e = t; e < EPG; e += TPB) {
        int d = dstp[e] - gbase;
        int s = srcp[e] - gbase;
        int p = atomicAdd(&cur[d], 1);
        csr[p] = (unsigned char)s;
    }
    __syncthreads();

    // ---------------- Phase F: fill padding slots with zero-row index 200 ----------------
    if (t < MG) {
        for (int p = cur[t]; p < roff[t + 1]; ++p) csr[p] = (unsigned char)200;
    }
    __syncthreads();

    const int f32lane = t & 31;
    const int islot   = t >> 5;   // 0..31

    // agg: hcur[d][f] = tanh(dinv[d]*sum_{p} bufX[csr[p]][f] + bias[f]);
    // archOff >= 0: also archive result to global as f16 at column offset archOff.
    auto agg_layer = [&](int archOff) {
        const int fq  = t & 7;
        const int f4  = fq << 2;
        const int dsl = t >> 3;   // 0..127
        for (int d = dsl; d < MG; d += 128) {
            const int p0 = roff[d], p1 = roff[d + 1];
            float a0 = 0.f, a1 = 0.f, a2 = 0.f, a3 = 0.f;
            for (int p = p0; p < p1; p += 4) {
                const unsigned q = *(const unsigned*)(csr + p);
                const float4 v0 = *(const float4*)(bufX + (q & 255u) * 36 + f4);
                const float4 v1 = *(const float4*)(bufX + ((q >> 8) & 255u) * 36 + f4);
                a0 += v0.x; a1 += v0.y; a2 += v0.z; a3 += v0.w;
                a0 += v1.x; a1 += v1.y; a2 += v1.z; a3 += v1.w;
                const float4 v2 = *(const float4*)(bufX + ((q >> 16) & 255u) * 36 + f4);
                const float4 v3 = *(const float4*)(bufX + (q >> 24) * 36 + f4);
                a0 += v2.x; a1 += v2.y; a2 += v2.z; a3 += v2.w;
                a0 += v3.x; a1 += v3.y; a2 += v3.z; a3 += v3.w;
            }
            const float dv = dinv[d];
            const float o0 = tanhf(dv * a0 + bias[f4 + 0]);
            const float o1 = tanhf(dv * a1 + bias[f4 + 1]);
            const float o2 = tanhf(dv * a2 + bias[f4 + 2]);
            const float o3 = tanhf(dv * a3 + bias[f4 + 3]);
            *(float4*)(hcur + d * 36 + f4) = make_float4(o0, o1, o2, o3);
            if (archOff >= 0) {
                const __half2 p01 = __floats2half2_rn(o0, o1);
                const __half2 p23 = __floats2half2_rn(o2, o3);
                __half2* dst = (__half2*)(arch + (size_t)(gbase + d) * 64 + archOff + f4);
                dst[0] = p01;
                dst[1] = p23;
            }
        }
    };

    auto gemm_mid = [&](const float* __restrict__ src) {
        // bufX = (src[200x32] @ W[32x32]) scaled by dinv[row]
        const int f = f32lane;
        {
            float acc0 = 0.f, acc1 = 0.f, acc2 = 0.f, acc3 = 0.f;
            #pragma unroll 2
            for (int k4 = 0; k4 < 8; ++k4) {
                const float w0 = wreg[k4 * 128 + 0  + f];
                const float w1 = wreg[k4 * 128 + 32 + f];
                const float w2 = wreg[k4 * 128 + 64 + f];
                const float w3 = wreg[k4 * 128 + 96 + f];
                float4 v;
                v = *(const float4*)(src + (islot      ) * 36 + k4 * 4); acc0 += v.x*w0 + v.y*w1 + v.z*w2 + v.w*w3;
                v = *(const float4*)(src + (islot + 32 ) * 36 + k4 * 4); acc1 += v.x*w0 + v.y*w1 + v.z*w2 + v.w*w3;
                v = *(const float4*)(src + (islot + 64 ) * 36 + k4 * 4); acc2 += v.x*w0 + v.y*w1 + v.z*w2 + v.w*w3;
                v = *(const float4*)(src + (islot + 96 ) * 36 + k4 * 4); acc3 += v.x*w0 + v.y*w1 + v.z*w2 + v.w*w3;
            }
            bufX[(islot      ) * 36 + f] = dinv[islot      ] * acc0;
            bufX[(islot + 32 ) * 36 + f] = dinv[islot + 32 ] * acc1;
            bufX[(islot + 64 ) * 36 + f] = dinv[islot + 64 ] * acc2;
            bufX[(islot + 96 ) * 36 + f] = dinv[islot + 96 ] * acc3;
        }
        {
            const int i2  = islot + 192;
            const int i2c = i2 < MG ? i2 : (MG - 1);
            float acc0 = 0.f, acc1 = 0.f, acc2 = 0.f;
            #pragma unroll 2
            for (int k4 = 0; k4 < 8; ++k4) {
                const float w0 = wreg[k4 * 128 + 0  + f];
                const float w1 = wreg[k4 * 128 + 32 + f];
                const float w2 = wreg[k4 * 128 + 64 + f];
                const float w3 = wreg[k4 * 128 + 96 + f];
                float4 v;
                v = *(const float4*)(src + (islot + 128) * 36 + k4 * 4); acc0 += v.x*w0 + v.y*w1 + v.z*w2 + v.w*w3;
                v = *(const float4*)(src + (islot + 160) * 36 + k4 * 4); acc1 += v.x*w0 + v.y*w1 + v.z*w2 + v.w*w3;
                v = *(const float4*)(src + (i2c        ) * 36 + k4 * 4); acc2 += v.x*w0 + v.y*w1 + v.z*w2 + v.w*w3;
            }
            bufX[(islot + 128) * 36 + f] = dinv[islot + 128] * acc0;
            bufX[(islot + 160) * 36 + f] = dinv[islot + 160] * acc1;
            if (i2 < MG) bufX[i2 * 36 + f] = dinv[i2] * acc2;
        }
    };

    // ---------------- Layer 1 GEMM: x[200x128] @ W1[128x32] ----------------
    // W1 staged in 8KB halves, 3 stagings total. Scalar accumulators only;
    // row group A = islot+{0,32,64,96}, group B = islot+{128,160,192(clamped)}.
    {
        const int f = f32lane;
        const float4* xv = (const float4*)xg;
        // ---- Group A, K-half 1 (wreg = W1 k-rows 0..63 from Phase A) ----
        float a0 = 0.f, a1 = 0.f, a2 = 0.f, a3 = 0.f;
        #pragma unroll 2
        for (int k4 = 0; k4 < 16; ++k4) {
            const float w0 = wreg[k4 * 128 + 0  + f];
            const float w1 = wreg[k4 * 128 + 32 + f];
            const float w2 = wreg[k4 * 128 + 64 + f];
            const float w3 = wreg[k4 * 128 + 96 + f];
            float4 v;
            v = xv[(islot      ) * 32 + k4]; a0 += v.x*w0 + v.y*w1 + v.z*w2 + v.w*w3;
            v = xv[(islot + 32 ) * 32 + k4]; a1 += v.x*w0 + v.y*w1 + v.z*w2 + v.w*w3;
            v = xv[(islot + 64 ) * 32 + k4]; a2 += v.x*w0 + v.y*w1 + v.z*w2 + v.w*w3;
            v = xv[(islot + 96 ) * 32 + k4]; a3 += v.x*w0 + v.y*w1 + v.z*w2 + v.w*w3;
        }
        __syncthreads();
        for (int idx = t; idx < 2048; idx += TPB) wreg[idx] = W1[2048 + idx];
        __syncthreads();
        // ---- Group A, K-half 2 (wreg = W1 k-rows 64..127) ----
        #pragma unroll 2
        for (int k4 = 0; k4 < 16; ++k4) {
            const float w0 = wreg[k4 * 128 + 0  + f];
            const float w1 = wreg[k4 * 128 + 32 + f];
            const float w2 = wreg[k4 * 128 + 64 + f];
            const float w3 = wreg[k4 * 128 + 96 + f];
            float4 v;
            v = xv[(islot      ) * 32 + 16 + k4]; a0 += v.x*w0 + v.y*w1 + v.z*w2 + v.w*w3;
            v = xv[(islot + 32 ) * 32 + 16 + k4]; a1 += v.x*w0 + v.y*w1 + v.z*w2 + v.w*w3;
            v = xv[(islot + 64 ) * 32 + 16 + k4]; a2 += v.x*w0 + v.y*w1 + v.z*w2 + v.w*w3;
            v = xv[(islot + 96 ) * 32 + 16 + k4]; a3 += v.x*w0 + v.y*w1 + v.z*w2 + v.w*w3;
        }
        bufX[(islot      ) * 36 + f] = dinv[islot      ] * a0;
        bufX[(islot + 32 ) * 36 + f] = dinv[islot + 32 ] * a1;
        bufX[(islot + 64 ) * 36 + f] = dinv[islot + 64 ] * a2;
        bufX[(islot + 96 ) * 36 + f] = dinv[islot + 96 ] * a3;
        // ---- Group B, K-half 2 first (wreg already = half 2) ----
        const int r6  = islot + 192;
        const int r6c = (r6 < MG) ? r6 : (MG - 1);
        float b0v = 0.f, b1v = 0.f, b2v = 0.f;
        #pragma unroll 2
        for (int k4 = 0; k4 < 16; ++k4) {
            const float w0 = wreg[k4 * 128 + 0  + f];
            const float w1 = wreg[k4 * 128 + 32 + f];
            const float w2 = wreg[k4 * 128 + 64 + f];
            const float w3 = wreg[k4 * 128 + 96 + f];
            float4 v;
            v = xv[(islot + 128) * 32 + 16 + k4]; b0v += v.x*w0 + v.y*w1 + v.z*w2 + v.w*w3;
            v = xv[(islot + 160) * 32 + 16 + k4]; b1v += v.x*w0 + v.y*w1 + v.z*w2 + v.w*w3;
            v = xv[(r6c        ) * 32 + 16 + k4]; b2v += v.x*w0 + v.y*w1 + v.z*w2 + v.w*w3;
        }
        __syncthreads();
        for (int idx = t; idx < 2048; idx += TPB) wreg[idx] = W1[idx];
        __syncthreads();
        // ---- Group B, K-half 1 ----
        #pragma unroll 2
        for (int k4 = 0; k4 < 16; ++k4) {
            const float w0 = wreg[k4 * 128 + 0  + f];
            const float w1 = wreg[k4 * 128 + 32 + f];
            const float w2 = wreg[k4 * 128 + 64 + f];
            const float w3 = wreg[k4 * 128 + 96 + f];
            float4 v;
            v = xv[(islot + 128) * 32 + k4]; b0v += v.x*w0 + v.y*w1 + v.z*w2 + v.w*w3;
            v = xv[(islot + 160) * 32 + k4]; b1v += v.x*w0 + v.y*w1 + v.z*w2 + v.w*w3;
            v = xv[(r6c        ) * 32 + k4]; b2v += v.x*w0 + v.y*w1 + v.z*w2 + v.w*w3;
        }
        bufX[(islot + 128) * 36 + f] = dinv[islot + 128] * b0v;
        bufX[(islot + 160) * 36 + f] = dinv[islot + 160] * b1v;
        if (r6 < MG) bufX[r6 * 36 + f] = dinv[r6] * b2v;
    }
    __syncthreads();
    agg_layer(0);    // h1 -> arch[:,0:32)
    __syncthreads();

    // ---------------- Layer 2 ----------------
    for (int idx = t; idx < 1024; idx += TPB) wreg[idx] = W2[idx];
    if (t < 32) bias[t] = b2[t];
    __syncthreads();
    gemm_mid(hcur);
    __syncthreads();
    agg_layer(32);   // h2 -> arch[:,32:64)
    __syncthreads();

    // ---------------- Layer 3 ----------------
    for (int idx = t; idx < 1024; idx += TPB) wreg[idx] = W3[idx];
    if (t < 32) bias[t] = b3[t];
    __syncthreads();
    gemm_mid(hcur);
    __syncthreads();
    agg_layer(-1);   // h3 stays in hcur (f32), not archived
    __syncthreads();

    // ---------------- Layer 4 (Fout=1): scl = dinv * (h3 @ W4); scl[200]=0 ----------------
    float* scl = (float*)(smem + OFF_CNT);   // 400 floats available (cnt+cur dead)
    if (t < MG) {
        float a = 0.f;
        #pragma unroll 8
        for (int k = 0; k < 32; ++k) a += hcur[t * 36 + k] * W4[k];
        scl[t] = dinv[t] * a;
    }
    if (t == 512) scl[200] = 0.f;
    __syncthreads();
    if (t < MG) {
        const int p0 = roff[t], p1 = roff[t + 1];
        float s = 0.f;
        for (int p = p0; p < p1; p += 4) {
            const unsigned q = *(const unsigned*)(csr + p);
            s += scl[q & 255u] + scl[(q >> 8) & 255u]
               + scl[(q >> 16) & 255u] + scl[q >> 24];
        }
        h4k[t] = tanhf(dinv[t] * s + b4[0]);
    }
    __syncthreads();

    // ---------------- SortPool: exact stable rank (desc value, asc index) ----------------
    if (t < 512) {
        const int i = t & 255;
        const int half = t >> 8;
        if (i < MG) {
            const float vi = h4k[i];
            int r = 0;
            const int j0 = half * 100, j1 = half * 100 + 100;
            for (int j = j0; j < j1; ++j) {
                const float vj = h4k[j];
                r += (vj > vi || (vj == vi && j < i)) ? 1 : 0;
            }
            atomicAdd(&rank[i], r);
        }
    }
    __syncthreads();
    if (t < MG) {
        const int r = rank[t];
        if (r < 30) ord[r] = t;
    }
    __syncthreads();

    // ---------------- Stage conv weights (bufX tail) + gather top-30 features ----------
    float* topv = bufX;           // [30][100] = 3000 floats
    float* cw   = bufX + 3104;    // cW1: [0,1552)  cW2: [1552,4112); ends at 7216 <= 7236
    for (int idx = t; idx < 1552; idx += TPB) cw[idx] = cW1[idx];
    for (int idx = t; idx < 2560; idx += TPB) cw[1552 + idx] = cW2[idx];
    if (t < 16) bias[t] = cb1[t];
    else if (t < 48) bias[t] = cb2[t - 16];
    for (int idx = t; idx < 2910; idx += TPB) {   // 30*97 grid-stride
        const int kk = idx / 97;
        const int ff = idx - kk * 97;
        const int nd = ord[kk];
        float v;
        if      (ff < 64) v = __half2float(arch[(size_t)(gbase + nd) * 64 + ff]);
        else if (ff < 96) v = hcur[nd * 36 + (ff - 64)];   // h3, f32
        else              v = h4k[nd];
        topv[kk * 100 + ff] = v;
    }
    __syncthreads();

    // conv scratch in hcur (dead after gather barrier)
    float* c1p2 = hcur;           // [16][30]
    float* c1pl = hcur + 480;     // [16][16]
    float* flat = hcur + 736;     // [352]
    float* hlin = hcur + 1088;    // [128]

    // ---------------- Conv1 (97->16 per slot) + ReLU ----------------
    if (t < 480) {
        const int o  = t & 15;
        const int tt = t >> 4;
        float a = bias[o];
        const float* wrow = cw + o * 97;
        const float* trow = topv + tt * 100;
        #pragma unroll 4
        for (int f = 0; f < 97; ++f) a += wrow[f] * trow[f];
        c1p2[o * 30 + tt] = fmaxf(a, 0.f);
    }
    __syncthreads();

    // ---------------- MaxPool1d(2,2): 30 -> 15 ----------------
    if (t < 240) {
        const int o  = t & 15;
        const int tp = t >> 4;
        c1pl[o * 16 + tp] = fmaxf(c1p2[o * 30 + 2 * tp], c1p2[o * 30 + 2 * tp + 1]);
    }
    __syncthreads();

    // ---------------- Conv2 (16->32, k=5) + ReLU -> flat; init hlin ----------------
    if (t < 352) {
        const int o  = t & 31;
        const int tt = t >> 5;
        float a = bias[16 + o];
        const float* w2r = cw + 1552 + o * 80;
        #pragma unroll
        for (int i2 = 0; i2 < 16; ++i2) {
            #pragma unroll
            for (int kk = 0; kk < 5; ++kk)
                a += w2r[i2 * 5 + kk] * c1pl[i2 * 16 + tt + kk];
        }
        flat[o * 11 + tt] = fmaxf(a, 0.f);
    } else if (t >= 512 && t < 640) {
        hlin[t - 512] = lb1[t - 512];
    }
    __syncthreads();

    // ---------------- Linear 352->128 (split-K over 8 groups) ----------------
    {
        const int f  = t & 127;
        const int kc = t >> 7;
        float a = 0.f;
        const int k0 = kc * 44;
        #pragma unroll 4
        for (int kk = k0; kk < k0 + 44; ++kk) a += flat[kk] * lW1[kk * 128 + f];
        atomicAdd(&hlin[f], a);
    }
    __syncthreads();

    // ---------------- ReLU -> Linear 128->1 -> sigmoid ----------------
    if (t < 128) {
        float p = fmaxf(hlin[t], 0.f) * lW2[t];
        #pragma unroll
        for (int off = 32; off > 0; off >>= 1) p += __shfl_down(p, off);
        if ((t & 63) == 0) red[t >> 6] = p;
    }
    __syncthreads();
    if (t == 0) {
        const float z = red[0] + red[1] + lb2[0];
        out[g] = 1.f / (1.f + expf(-z));
    }
}

extern "C" void kernel_launch(void* const* d_in, const int* in_sizes, int n_in,
                              void* d_out, int out_size, void* d_ws, size_t ws_size,
                              hipStream_t stream) {
    (void)in_sizes; (void)n_in; (void)out_size; (void)ws_size;
    const float* x   = (const float*)d_in[0];
    const int*   ei  = (const int*)d_in[1];
    const float* W1  = (const float*)d_in[3];  const float* b1  = (const float*)d_in[4];
    const float* W2  = (const float*)d_in[5];  const float* b2  = (const float*)d_in[6];
    const float* W3  = (const float*)d_in[7];  const float* b3  = (const float*)d_in[8];
    const float* W4  = (const float*)d_in[9];  const float* b4  = (const float*)d_in[10];
    const float* cW1 = (const float*)d_in[11]; const float* cb1 = (const float*)d_in[12];
    const float* cW2 = (const float*)d_in[13]; const float* cb2 = (const float*)d_in[14];
    const float* lW1 = (const float*)d_in[15]; const float* lb1 = (const float*)d_in[16];
    const float* lW2 = (const float*)d_in[17]; const float* lb2 = (const float*)d_in[18];
    float* out = (float*)d_out;
    __half* arch = (__half*)d_ws;                          // 13.1 MB
    float* wpack = (float*)((char*)d_ws + ARCH_BYTES);     // +223 KB

    hipFuncSetAttribute((const void*)dgcnn_kernel,
                        hipFuncAttributeMaxDynamicSharedMemorySize, SMEM_BYTES);

    pack_weights<<<64, 256, 0, stream>>>(
        W1, b1, W2, b2, W3, b3, W4, b4,
        cW1, cb1, cW2, cb2, lW1, lb1, lW2, lb2, wpack);

    dgcnn_kernel<<<GRID, TPB, SMEM_BYTES, stream>>>(x, ei, wpack, arch, out);
}

// Round 8
// 268.074 us; speedup vs baseline: 1.0726x; 1.0726x over previous
//
#include <hip/hip_runtime.h>
#include <hip/hip_fp16.h>

// DGCNN forward, fully fused: one workgroup per graph, TPB=512 (8 waves),
// 2 blocks/CU co-resident -> single dispatch round, overlapped barrier groups.
// f32 everywhere on the sort-key-critical chain; h1/h2 archived to global
// scratch as f16 (conv features only); h3 read back from LDS in f32.
//
// Occupancy rules learned R3-R7 (MI355X, 1024-thread blocks):
//  * NO launch_bounds min-waves / waves_per_eu hints -> allocator over-shrinks
//    to 32 VGPR with ~200 MB scratch spill traffic.
//  * Two 16-wave blocks co-schedule only at VGPR<=32 (empirical pool ~256/SIMD
//    for co-residency); at VGPR=48 they don't. 8-wave blocks need only
//    4 waves/SIMD x 48 VGPR = 192 -> fits.
//  * SGPR count (80 vs 96) does NOT gate occupancy here (R7 falsified).

#define TPB   512
#define GRID  512
#define MG    200
#define EPG   6400
#define EE    (512 * EPG)

// ---- LDS layout (byte offsets). Total 74,240 B -> 2 blocks/CU (148.5/160 KiB) ----
#define OFF_BUFX 0        // f32[201*36] rows 0..200 (row 200 = zeros); later topv[30][100] + conv W
#define OFF_HCUR 28944    // f32[200*36] current-layer h (f32); later conv scratch
#define OFF_CSR  57744    // u8[7200]    CSR (rows padded to x4 entries, pad -> 200)
#define OFF_ROFF 64944    // i32[201] row offsets (padded units)
#define OFF_CNT  65760    // i32[200] degree counts   \ scl f32[201] aliases CNT..CUR
#define OFF_CUR  66560    // i32[200] cursors         /
#define OFF_DINV 67360    // f32[200]
#define OFF_H4   68160    // f32[200] sort key
#define OFF_RANK 68960    // i32[200]
#define OFF_ORD  69760    // i32[30]
#define OFF_BIAS 69880    // f32[48]
#define OFF_RED  70072    // f32[16] (+8 pad)
#define OFF_WREG 70144    // f32[1024] W2/W3 stage (L1 reads W1 straight from L1$)
#define SMEM_BYTES 74240

__global__ __launch_bounds__(TPB)
void dgcnn_kernel(
    const float* __restrict__ x,
    const int*   __restrict__ ei,
    const float* __restrict__ W1, const float* __restrict__ b1,
    const float* __restrict__ W2, const float* __restrict__ b2,
    const float* __restrict__ W3, const float* __restrict__ b3,
    const float* __restrict__ W4, const float* __restrict__ b4,
    const float* __restrict__ cW1, const float* __restrict__ cb1,
    const float* __restrict__ cW2, const float* __restrict__ cb2,
    const float* __restrict__ lW1, const float* __restrict__ lb1,
    const float* __restrict__ lW2, const float* __restrict__ lb2,
    __half* __restrict__ arch,     // [512][200][64] f16 archive of h1|h2
    float* __restrict__ out)
{
    extern __shared__ unsigned char smem[];
    float* bufX = (float*)(smem + OFF_BUFX);
    float* hcur = (float*)(smem + OFF_HCUR);
    unsigned char* csr = (unsigned char*)(smem + OFF_CSR);
    int*   roff = (int*)(smem + OFF_ROFF);
    int*   cnt  = (int*)(smem + OFF_CNT);
    int*   cur  = (int*)(smem + OFF_CUR);
    float* dinv = (float*)(smem + OFF_DINV);
    float* h4k  = (float*)(smem + OFF_H4);
    int*   rank = (int*)(smem + OFF_RANK);
    int*   ord  = (int*)(smem + OFF_ORD);
    float* bias = (float*)(smem + OFF_BIAS);
    float* red  = (float*)(smem + OFF_RED);
    float* wreg = (float*)(smem + OFF_WREG);

    const int g = blockIdx.x;
    const int t = threadIdx.x;
    const int gbase = g * MG;
    const float* xg   = x + (size_t)gbase * 128;
    const int*   srcp = ei + (size_t)g * EPG;
    const int*   dstp = ei + (size_t)EE + (size_t)g * EPG;

    // ---------------- Phase A: bias b1, zero counters + zero row ----------------
    if (t < 32) bias[t] = b1[t];
    if (t < MG) { cnt[t] = 0; rank[t] = 0; }
    if (t >= 256 && t < 292) bufX[200 * 36 + (t - 256)] = 0.f;   // zero row 200
    __syncthreads();

    // ---------------- Phase B: in-degree count ----------------
    for (int e = t; e < EPG; e += TPB) atomicAdd(&cnt[dstp[e] - gbase], 1);
    __syncthreads();

    // ---------------- Phase C: dinv + prefix scan over PADDED row lengths ----------------
    if (t >= 256 && t < 256 + MG) {
        int i = t - 256;
        dinv[i] = 1.0f / sqrtf((float)(cnt[i] + 1));
    }
    if (t < 64) {
        if (t == 0) roff[0] = 0;
        int carry = 0;
        #pragma unroll
        for (int c = 0; c < 4; ++c) {
            const int i = c * 64 + t;
            int v = (i < MG) ? ((cnt[i] + 4) & ~3) : 0;   // self-loop +1, pad to x4
            #pragma unroll
            for (int off = 1; off < 64; off <<= 1) {
                int u = __shfl_up(v, off);
                if (t >= (int)off) v += u;
            }
            if (i < MG) roff[i + 1] = carry + v;
            carry += __shfl(v, 63);
        }
    }
    __syncthreads();

    // ---------------- Phase D: self-loop entry + cursors ----------------
    if (t < MG) {
        int p = roff[t];
        csr[p] = (unsigned char)t;
        cur[t] = p + 1;
    }
    __syncthreads();

    // ---------------- Phase E: CSR placement ----------------
    for (int e = t; e < EPG; e += TPB) {
        int d = dstp[e] - gbase;
        int s = srcp[e] - gbase;
        int p = atomicAdd(&cur[d], 1);
        csr[p] = (unsigned char)s;
    }
    __syncthreads();

    // ---------------- Phase F: fill padding slots with zero-row index 200 ----------------
    if (t < MG) {
        for (int p = cur[t]; p < roff[t + 1]; ++p) csr[p] = (unsigned char)200;
    }
    __syncthreads();

    const int f32lane = t & 31;   // feature (output col) 0..31
    const int islot   = t >> 5;   // row slot 0..15

    // agg: hcur[d][f] = tanh(dinv[d]*sum_{p} bufX[csr[p]][f] + bias[f]);
    // archOff >= 0: also archive result to global as f16 at column offset archOff.
    auto agg_layer = [&](int archOff) {
        const int fq  = t & 7;
        const int f4  = fq << 2;
        const int dsl = t >> 3;   // 0..63
        for (int d = dsl; d < MG; d += 64) {
            const int p0 = roff[d], p1 = roff[d + 1];
            float a0 = 0.f, a1 = 0.f, a2 = 0.f, a3 = 0.f;
            for (int p = p0; p < p1; p += 4) {
                const unsigned q = *(const unsigned*)(csr + p);
                const float4 v0 = *(const float4*)(bufX + (q & 255u) * 36 + f4);
                const float4 v1 = *(const float4*)(bufX + ((q >> 8) & 255u) * 36 + f4);
                a0 += v0.x; a1 += v0.y; a2 += v0.z; a3 += v0.w;
                a0 += v1.x; a1 += v1.y; a2 += v1.z; a3 += v1.w;
                const float4 v2 = *(const float4*)(bufX + ((q >> 16) & 255u) * 36 + f4);
                const float4 v3 = *(const float4*)(bufX + (q >> 24) * 36 + f4);
                a0 += v2.x; a1 += v2.y; a2 += v2.z; a3 += v2.w;
                a0 += v3.x; a1 += v3.y; a2 += v3.z; a3 += v3.w;
            }
            const float dv = dinv[d];
            const float o0 = tanhf(dv * a0 + bias[f4 + 0]);
            const float o1 = tanhf(dv * a1 + bias[f4 + 1]);
            const float o2 = tanhf(dv * a2 + bias[f4 + 2]);
            const float o3 = tanhf(dv * a3 + bias[f4 + 3]);
            *(float4*)(hcur + d * 36 + f4) = make_float4(o0, o1, o2, o3);
            if (archOff >= 0) {
                const __half2 p01 = __floats2half2_rn(o0, o1);
                const __half2 p23 = __floats2half2_rn(o2, o3);
                __half2* dst = (__half2*)(arch + (size_t)(gbase + d) * 64 + archOff + f4);
                dst[0] = p01;
                dst[1] = p23;
            }
        }
    };

    auto gemm_mid = [&](const float* __restrict__ src) {
        // bufX = (src[200x32] @ W[32x32]) scaled by dinv[row]; W staged in wreg.
        const int f = f32lane;
        #pragma unroll
        for (int j0 = 0; j0 < 12; j0 += 4) {
            const int r0 = islot + 16 * j0;
            float a0 = 0.f, a1 = 0.f, a2 = 0.f, a3 = 0.f;
            #pragma unroll 2
            for (int k4 = 0; k4 < 8; ++k4) {
                const float w0 = wreg[k4 * 128 + 0  + f];
                const float w1 = wreg[k4 * 128 + 32 + f];
                const float w2 = wreg[k4 * 128 + 64 + f];
                const float w3 = wreg[k4 * 128 + 96 + f];
                float4 v;
                v = *(const float4*)(src + (r0      ) * 36 + k4 * 4); a0 += v.x*w0 + v.y*w1 + v.z*w2 + v.w*w3;
                v = *(const float4*)(src + (r0 + 16 ) * 36 + k4 * 4); a1 += v.x*w0 + v.y*w1 + v.z*w2 + v.w*w3;
                v = *(const float4*)(src + (r0 + 32 ) * 36 + k4 * 4); a2 += v.x*w0 + v.y*w1 + v.z*w2 + v.w*w3;
                v = *(const float4*)(src + (r0 + 48 ) * 36 + k4 * 4); a3 += v.x*w0 + v.y*w1 + v.z*w2 + v.w*w3;
            }
            bufX[(r0      ) * 36 + f] = dinv[r0      ] * a0;
            bufX[(r0 + 16 ) * 36 + f] = dinv[r0 + 16 ] * a1;
            bufX[(r0 + 32 ) * 36 + f] = dinv[r0 + 32 ] * a2;
            bufX[(r0 + 48 ) * 36 + f] = dinv[r0 + 48 ] * a3;
        }
        if (islot < 8) {   // rows 192..199
            const int r = 192 + islot;
            float a0 = 0.f;
            #pragma unroll 2
            for (int k4 = 0; k4 < 8; ++k4) {
                const float w0 = wreg[k4 * 128 + 0  + f];
                const float w1 = wreg[k4 * 128 + 32 + f];
                const float w2 = wreg[k4 * 128 + 64 + f];
                const float w3 = wreg[k4 * 128 + 96 + f];
                const float4 v = *(const float4*)(src + r * 36 + k4 * 4);
                a0 += v.x*w0 + v.y*w1 + v.z*w2 + v.w*w3;
            }
            bufX[r * 36 + f] = dinv[r] * a0;
        }
    };

    // ---------------- Layer 1 GEMM: x[200x128] @ W1[128x32] ----------------
    // W1 read directly from global (16 KB, L1-hot, broadcast across lanes).
    // 4-row passes, named scalar accumulators, no barriers in this phase.
    {
        const int f = f32lane;
        const float4* xv = (const float4*)xg;
        #pragma unroll
        for (int j0 = 0; j0 < 12; j0 += 4) {
            const int r0 = islot + 16 * j0;
            float a0 = 0.f, a1 = 0.f, a2 = 0.f, a3 = 0.f;
            #pragma unroll 2
            for (int k4 = 0; k4 < 32; ++k4) {
                const float w0 = W1[k4 * 128 + 0  + f];
                const float w1 = W1[k4 * 128 + 32 + f];
                const float w2 = W1[k4 * 128 + 64 + f];
                const float w3 = W1[k4 * 128 + 96 + f];
                float4 v;
                v = xv[(r0      ) * 32 + k4]; a0 += v.x*w0 + v.y*w1 + v.z*w2 + v.w*w3;
                v = xv[(r0 + 16 ) * 32 + k4]; a1 += v.x*w0 + v.y*w1 + v.z*w2 + v.w*w3;
                v = xv[(r0 + 32 ) * 32 + k4]; a2 += v.x*w0 + v.y*w1 + v.z*w2 + v.w*w3;
                v = xv[(r0 + 48 ) * 32 + k4]; a3 += v.x*w0 + v.y*w1 + v.z*w2 + v.w*w3;
            }
            bufX[(r0      ) * 36 + f] = dinv[r0      ] * a0;
            bufX[(r0 + 16 ) * 36 + f] = dinv[r0 + 16 ] * a1;
            bufX[(r0 + 32 ) * 36 + f] = dinv[r0 + 32 ] * a2;
            bufX[(r0 + 48 ) * 36 + f] = dinv[r0 + 48 ] * a3;
        }
        if (islot < 8) {   // rows 192..199
            const int r = 192 + islot;
            float a0 = 0.f;
            #pragma unroll 2
            for (int k4 = 0; k4 < 32; ++k4) {
                const float w0 = W1[k4 * 128 + 0  + f];
                const float w1 = W1[k4 * 128 + 32 + f];
                const float w2 = W1[k4 * 128 + 64 + f];
                const float w3 = W1[k4 * 128 + 96 + f];
                const float4 v = xv[r * 32 + k4];
                a0 += v.x*w0 + v.y*w1 + v.z*w2 + v.w*w3;
            }
            bufX[r * 36 + f] = dinv[r] * a0;
        }
    }
    __syncthreads();
    agg_layer(0);    // h1 -> arch[:,0:32)
    __syncthreads();

    // ---------------- Layer 2 ----------------
    for (int idx = t; idx < 1024; idx += TPB) wreg[idx] = W2[idx];
    if (t < 32) bias[t] = b2[t];
    __syncthreads();
    gemm_mid(hcur);
    __syncthreads();
    agg_layer(32);   // h2 -> arch[:,32:64)
    __syncthreads();

    // ---------------- Layer 3 ----------------
    for (int idx = t; idx < 1024; idx += TPB) wreg[idx] = W3[idx];
    if (t < 32) bias[t] = b3[t];
    __syncthreads();
    gemm_mid(hcur);
    __syncthreads();
    agg_layer(-1);   // h3 stays in hcur (f32), not archived
    __syncthreads();

    // ---------------- Layer 4 (Fout=1): scl = dinv * (h3 @ W4); scl[200]=0 ----------------
    float* scl = (float*)(smem + OFF_CNT);   // 400 floats available (cnt+cur dead)
    if (t < MG) {
        float a = 0.f;
        #pragma unroll 8
        for (int k = 0; k < 32; ++k) a += hcur[t * 36 + k] * W4[k];
        scl[t] = dinv[t] * a;
    }
    if (t == 200) scl[200] = 0.f;
    __syncthreads();
    if (t < MG) {
        const int p0 = roff[t], p1 = roff[t + 1];
        float s = 0.f;
        for (int p = p0; p < p1; p += 4) {
            const unsigned q = *(const unsigned*)(csr + p);
            s += scl[q & 255u] + scl[(q >> 8) & 255u]
               + scl[(q >> 16) & 255u] + scl[q >> 24];
        }
        h4k[t] = tanhf(dinv[t] * s + b4[0]);
    }
    __syncthreads();

    // ---------------- SortPool: exact stable rank (desc value, asc index) ----------------
    {
        const int i = t & 255;
        const int half = t >> 8;   // 0 or 1
        if (i < MG) {
            const float vi = h4k[i];
            int r = 0;
            const int j0 = half * 100, j1 = half * 100 + 100;
            for (int j = j0; j < j1; ++j) {
                const float vj = h4k[j];
                r += (vj > vi || (vj == vi && j < i)) ? 1 : 0;
            }
            atomicAdd(&rank[i], r);
        }
    }
    __syncthreads();
    if (t < MG) {
        const int r = rank[t];
        if (r < 30) ord[r] = t;
    }
    __syncthreads();

    // ---------------- Stage conv weights (bufX tail) + gather top-30 features ----------
    float* topv = bufX;           // [30][100] = 3000 floats
    float* cw   = bufX + 3104;    // cW1: [0,1552)  cW2: [1552,4112); ends at 7216 <= 7236
    for (int idx = t; idx < 1552; idx += TPB) cw[idx] = cW1[idx];
    for (int idx = t; idx < 2560; idx += TPB) cw[1552 + idx] = cW2[idx];
    if (t < 16) bias[t] = cb1[t];
    else if (t < 48) bias[t] = cb2[t - 16];
    for (int idx = t; idx < 2910; idx += TPB) {   // 30*97 grid-stride
        const int kk = idx / 97;
        const int ff = idx - kk * 97;
        const int nd = ord[kk];
        float v;
        if      (ff < 64) v = __half2float(arch[(size_t)(gbase + nd) * 64 + ff]);
        else if (ff < 96) v = hcur[nd * 36 + (ff - 64)];   // h3, f32
        else              v = h4k[nd];
        topv[kk * 100 + ff] = v;
    }
    __syncthreads();

    // conv scratch in hcur (dead after gather barrier)
    float* c1p2 = hcur;           // [16][30]
    float* c1pl = hcur + 480;     // [16][16]
    float* flat = hcur + 736;     // [352]
    float* hlin = hcur + 1088;    // [128]

    // ---------------- Conv1 (97->16 per slot) + ReLU ----------------
    if (t < 480) {
        const int o  = t & 15;
        const int tt = t >> 4;
        float a = bias[o];
        const float* wrow = cw + o * 97;
        const float* trow = topv + tt * 100;
        #pragma unroll 4
        for (int f = 0; f < 97; ++f) a += wrow[f] * trow[f];
        c1p2[o * 30 + tt] = fmaxf(a, 0.f);
    }
    __syncthreads();

    // ---------------- MaxPool1d(2,2): 30 -> 15 ----------------
    if (t < 240) {
        const int o  = t & 15;
        const int tp = t >> 4;
        c1pl[o * 16 + tp] = fmaxf(c1p2[o * 30 + 2 * tp], c1p2[o * 30 + 2 * tp + 1]);
    }
    __syncthreads();

    // ---------------- Conv2 (16->32, k=5) + ReLU -> flat; init hlin ----------------
    if (t < 352) {
        const int o  = t & 31;
        const int tt = t >> 5;
        float a = bias[16 + o];
        const float* w2r = cw + 1552 + o * 80;
        #pragma unroll
        for (int i2 = 0; i2 < 16; ++i2) {
            #pragma unroll
            for (int kk = 0; kk < 5; ++kk)
                a += w2r[i2 * 5 + kk] * c1pl[i2 * 16 + tt + kk];
        }
        flat[o * 11 + tt] = fmaxf(a, 0.f);
    } else if (t >= 352 && t < 480) {
        hlin[t - 352] = lb1[t - 352];
    }
    __syncthreads();

    // ---------------- Linear 352->128 (split-K over 4 groups of 88) ----------------
    {
        const int f  = t & 127;
        const int kc = t >> 7;   // 0..3
        float a = 0.f;
        const int k0 = kc * 88;
        #pragma unroll 4
        for (int kk = k0; kk < k0 + 88; ++kk) a += flat[kk] * lW1[kk * 128 + f];
        atomicAdd(&hlin[f], a);
    }
    __syncthreads();

    // ---------------- ReLU -> Linear 128->1 -> sigmoid ----------------
    if (t < 128) {
        float p = fmaxf(hlin[t], 0.f) * lW2[t];
        #pragma unroll
        for (int off = 32; off > 0; off >>= 1) p += __shfl_down(p, off);
        if ((t & 63) == 0) red[t >> 6] = p;
    }
    __syncthreads();
    if (t == 0) {
        const float z = red[0] + red[1] + lb2[0];
        out[g] = 1.f / (1.f + expf(-z));
    }
}

extern "C" void kernel_launch(void* const* d_in, const int* in_sizes, int n_in,
                              void* d_out, int out_size, void* d_ws, size_t ws_size,
                              hipStream_t stream) {
    (void)in_sizes; (void)n_in; (void)out_size; (void)ws_size;
    const float* x   = (const float*)d_in[0];
    const int*   ei  = (const int*)d_in[1];
    const float* W1  = (const float*)d_in[3];  const float* b1  = (const float*)d_in[4];
    const float* W2  = (const float*)d_in[5];  const float* b2  = (const float*)d_in[6];
    const float* W3  = (const float*)d_in[7];  const float* b3  = (const float*)d_in[8];
    const float* W4  = (const float*)d_in[9];  const float* b4  = (const float*)d_in[10];
    const float* cW1 = (const float*)d_in[11]; const float* cb1 = (const float*)d_in[12];
    const float* cW2 = (const float*)d_in[13]; const float* cb2 = (const float*)d_in[14];
    const float* lW1 = (const float*)d_in[15]; const float* lb1 = (const float*)d_in[16];
    const float* lW2 = (const float*)d_in[17]; const float* lb2 = (const float*)d_in[18];
    float* out = (float*)d_out;
    __half* arch = (__half*)d_ws;   // needs 512*200*64*2 = 13.1 MB

    hipFuncSetAttribute((const void*)dgcnn_kernel,
                        hipFuncAttributeMaxDynamicSharedMemorySize, SMEM_BYTES);

    dgcnn_kernel<<<GRID, TPB, SMEM_BYTES, stream>>>(
        x, ei, W1, b1, W2, b2, W3, b3, W4, b4,
        cW1, cb1, cW2, cb2, lW1, lb1, lW2, lb2, arch, out);
}

// Round 9
// 264.948 us; speedup vs baseline: 1.0852x; 1.0118x over previous
//
#include <hip/hip_runtime.h>
#include <hip/hip_fp16.h>

// DGCNN forward, fully fused: one workgroup per graph, TPB=512 (8 waves),
// 2 blocks/CU co-resident. f32 on the entire sort-key chain; h1/h2 archived
// to global f16 (conv features only); h3 read back from LDS f32.
//
// Occupancy rules learned R3-R8 (MI355X):
//  * NO launch_bounds min-waves / waves_per_eu hints -> allocator over-shrinks
//    to 32 VGPR and spills ~200 MB/launch to scratch.
//  * 16-wave blocks only co-schedule at VGPR<=32; 8-wave blocks co-schedule
//    at 48 VGPR (4 waves/SIMD x 48 = 192 <= ~256 pool).
//  * VALU issue is the floor (~55 us/CU measured R8); rest is barrier idle.
// R9: edge-count overlapped with L1 GEMM (scale deferred - identical math),
// fast tanh (exp-based, monotone), 2 fewer barriers via in-phase W staging.

#define TPB   512
#define GRID  512
#define MG    200
#define EPG   6400
#define EE    (512 * EPG)

// ---- LDS layout (byte offsets). Total 74,304 B -> 2 blocks/CU (148.6/160 KiB) ----
#define OFF_BUFX 0        // f32[201*36] rows 0..200 (row 200 = zeros); later topv[30][100] + conv W
#define OFF_HCUR 28944    // f32[200*36] current-layer h (f32); later conv scratch
#define OFF_CSR  57744    // u8[7200]    CSR (rows padded to x4 entries, pad -> 200)
#define OFF_ROFF 64944    // i32[201] row offsets (padded units)
#define OFF_CNT  65760    // i32[200] degree counts   \ scl f32[201] aliases CNT..CUR
#define OFF_CUR  66560    // i32[200] cursors         /
#define OFF_DINV 67360    // f32[200]
#define OFF_H4   68160    // f32[200] sort key
#define OFF_RANK 68960    // i32[200]
#define OFF_ORD  69760    // i32[30]
#define OFF_BIAS 69880    // f32[64]  double-buffered layer bias (b1/b3 in [0,32), b2 in [32,64))
#define OFF_RED  70136    // f32[16] (+8 pad)
#define OFF_WREG 70208    // f32[1024] W2/W3 stage (L1 GEMM reads W1 from L1$)
#define SMEM_BYTES 74304

__device__ __forceinline__ float fast_tanh(float x) {
    // monotone, ~4 ulp; saturates correctly for |x| large (exp->inf or 0)
    const float e = __expf(2.0f * x);
    return 1.0f - 2.0f / (e + 1.0f);
}

__global__ __launch_bounds__(TPB)
void dgcnn_kernel(
    const float* __restrict__ x,
    const int*   __restrict__ ei,
    const float* __restrict__ W1, const float* __restrict__ b1,
    const float* __restrict__ W2, const float* __restrict__ b2,
    const float* __restrict__ W3, const float* __restrict__ b3,
    const float* __restrict__ W4, const float* __restrict__ b4,
    const float* __restrict__ cW1, const float* __restrict__ cb1,
    const float* __restrict__ cW2, const float* __restrict__ cb2,
    const float* __restrict__ lW1, const float* __restrict__ lb1,
    const float* __restrict__ lW2, const float* __restrict__ lb2,
    __half* __restrict__ arch,     // [512][200][64] f16 archive of h1|h2
    float* __restrict__ out)
{
    extern __shared__ unsigned char smem[];
    float* bufX = (float*)(smem + OFF_BUFX);
    float* hcur = (float*)(smem + OFF_HCUR);
    unsigned char* csr = (unsigned char*)(smem + OFF_CSR);
    int*   roff = (int*)(smem + OFF_ROFF);
    int*   cnt  = (int*)(smem + OFF_CNT);
    int*   cur  = (int*)(smem + OFF_CUR);
    float* dinv = (float*)(smem + OFF_DINV);
    float* h4k  = (float*)(smem + OFF_H4);
    int*   rank = (int*)(smem + OFF_RANK);
    int*   ord  = (int*)(smem + OFF_ORD);
    float* bias = (float*)(smem + OFF_BIAS);
    float* red  = (float*)(smem + OFF_RED);
    float* wreg = (float*)(smem + OFF_WREG);

    const int g = blockIdx.x;
    const int t = threadIdx.x;
    const int gbase = g * MG;
    const float* xg   = x + (size_t)gbase * 128;
    const int*   srcp = ei + (size_t)g * EPG;
    const int*   dstp = ei + (size_t)EE + (size_t)g * EPG;

    // ---------------- Phase A: bias b1, zero counters + zero row ----------------
    if (t < 32) bias[t] = b1[t];
    if (t < MG) { cnt[t] = 0; rank[t] = 0; }
    if (t >= 256 && t < 292) bufX[200 * 36 + (t - 256)] = 0.f;   // zero row 200
    __syncthreads();

    const int f32lane = t & 31;   // feature (output col) 0..31
    const int islot   = t >> 5;   // row slot 0..15

    // ---------------- Phase B: edge in-degree count (int4) + L1 GEMM, one phase ----------
    // The two are independent: edge-stream latency + LDS atomics hide under
    // the 819k-FMA GEMM. GEMM writes UNSCALED xw (dinv applied in Phase D;
    // identical arithmetic: acc*dinv either way).
    {
        const int4* d4p = (const int4*)dstp;
        for (int e4 = t; e4 < EPG / 4; e4 += TPB) {
            const int4 d4 = d4p[e4];
            atomicAdd(&cnt[d4.x - gbase], 1);
            atomicAdd(&cnt[d4.y - gbase], 1);
            atomicAdd(&cnt[d4.z - gbase], 1);
            atomicAdd(&cnt[d4.w - gbase], 1);
        }
    }
    {
        const int f = f32lane;
        const float4* xv = (const float4*)xg;
        #pragma unroll
        for (int j0 = 0; j0 < 12; j0 += 4) {
            const int r0 = islot + 16 * j0;
            float a0 = 0.f, a1 = 0.f, a2 = 0.f, a3 = 0.f;
            #pragma unroll 2
            for (int k4 = 0; k4 < 32; ++k4) {
                const float w0 = W1[k4 * 128 + 0  + f];
                const float w1 = W1[k4 * 128 + 32 + f];
                const float w2 = W1[k4 * 128 + 64 + f];
                const float w3 = W1[k4 * 128 + 96 + f];
                float4 v;
                v = xv[(r0      ) * 32 + k4]; a0 += v.x*w0 + v.y*w1 + v.z*w2 + v.w*w3;
                v = xv[(r0 + 16 ) * 32 + k4]; a1 += v.x*w0 + v.y*w1 + v.z*w2 + v.w*w3;
                v = xv[(r0 + 32 ) * 32 + k4]; a2 += v.x*w0 + v.y*w1 + v.z*w2 + v.w*w3;
                v = xv[(r0 + 48 ) * 32 + k4]; a3 += v.x*w0 + v.y*w1 + v.z*w2 + v.w*w3;
            }
            bufX[(r0      ) * 36 + f] = a0;
            bufX[(r0 + 16 ) * 36 + f] = a1;
            bufX[(r0 + 32 ) * 36 + f] = a2;
            bufX[(r0 + 48 ) * 36 + f] = a3;
        }
        if (islot < 8) {   // rows 192..199
            const int r = 192 + islot;
            float a0 = 0.f;
            #pragma unroll 2
            for (int k4 = 0; k4 < 32; ++k4) {
                const float w0 = W1[k4 * 128 + 0  + f];
                const float w1 = W1[k4 * 128 + 32 + f];
                const float w2 = W1[k4 * 128 + 64 + f];
                const float w3 = W1[k4 * 128 + 96 + f];
                const float4 v = xv[r * 32 + k4];
                a0 += v.x*w0 + v.y*w1 + v.z*w2 + v.w*w3;
            }
            bufX[r * 36 + f] = a0;
        }
    }
    __syncthreads();

    // ---------------- Phase C: dinv + prefix scan over PADDED row lengths ----------------
    if (t >= 256 && t < 256 + MG) {
        int i = t - 256;
        dinv[i] = 1.0f / sqrtf((float)(cnt[i] + 1));
    }
    if (t < 64) {
        if (t == 0) roff[0] = 0;
        int carry = 0;
        #pragma unroll
        for (int c = 0; c < 4; ++c) {
            const int i = c * 64 + t;
            int v = (i < MG) ? ((cnt[i] + 4) & ~3) : 0;   // self-loop +1, pad to x4
            #pragma unroll
            for (int off = 1; off < 64; off <<= 1) {
                int u = __shfl_up(v, off);
                if (t >= (int)off) v += u;
            }
            if (i < MG) roff[i + 1] = carry + v;
            carry += __shfl(v, 63);
        }
    }
    __syncthreads();

    // ---------------- Phase D: self-loop entry + cursors + dinv-scale bufX ----------------
    if (t < MG) {
        int p = roff[t];
        csr[p] = (unsigned char)t;
        cur[t] = p + 1;
    }
    {   // bufX[r][f] *= dinv[r]   (200x32, 12.5 ops/thread)
        for (int r = islot; r < MG; r += 16) {
            bufX[r * 36 + f32lane] *= dinv[r];
        }
    }
    __syncthreads();

    // ---------------- Phase E: CSR placement (int4 edge loads) ----------------
    {
        const int4* s4p = (const int4*)srcp;
        const int4* d4p = (const int4*)dstp;
        for (int e4 = t; e4 < EPG / 4; e4 += TPB) {
            const int4 s4 = s4p[e4];
            const int4 d4 = d4p[e4];
            int p;
            p = atomicAdd(&cur[d4.x - gbase], 1); csr[p] = (unsigned char)(s4.x - gbase);
            p = atomicAdd(&cur[d4.y - gbase], 1); csr[p] = (unsigned char)(s4.y - gbase);
            p = atomicAdd(&cur[d4.z - gbase], 1); csr[p] = (unsigned char)(s4.z - gbase);
            p = atomicAdd(&cur[d4.w - gbase], 1); csr[p] = (unsigned char)(s4.w - gbase);
        }
    }
    __syncthreads();

    // ---------------- Phase F: fill padding slots with zero-row index 200 ----------------
    if (t < MG) {
        for (int p = cur[t]; p < roff[t + 1]; ++p) csr[p] = (unsigned char)200;
    }
    __syncthreads();

    // agg: hcur[d][f] = tanh(dinv[d]*sum_{p} bufX[csr[p]][f] + bias[bb+f]);
    // archOff >= 0: also archive to global f16 at column offset archOff.
    auto agg_layer = [&](int archOff, int bb) {
        const int fq  = t & 7;
        const int f4  = fq << 2;
        const int dsl = t >> 3;   // 0..63
        for (int d = dsl; d < MG; d += 64) {
            const int p0 = roff[d], p1 = roff[d + 1];
            float a0 = 0.f, a1 = 0.f, a2 = 0.f, a3 = 0.f;
            for (int p = p0; p < p1; p += 4) {
                const unsigned q = *(const unsigned*)(csr + p);
                const float4 v0 = *(const float4*)(bufX + (q & 255u) * 36 + f4);
                const float4 v1 = *(const float4*)(bufX + ((q >> 8) & 255u) * 36 + f4);
                a0 += v0.x; a1 += v0.y; a2 += v0.z; a3 += v0.w;
                a0 += v1.x; a1 += v1.y; a2 += v1.z; a3 += v1.w;
                const float4 v2 = *(const float4*)(bufX + ((q >> 16) & 255u) * 36 + f4);
                const float4 v3 = *(const float4*)(bufX + (q >> 24) * 36 + f4);
                a0 += v2.x; a1 += v2.y; a2 += v2.z; a3 += v2.w;
                a0 += v3.x; a1 += v3.y; a2 += v3.z; a3 += v3.w;
            }
            const float dv = dinv[d];
            const float o0 = fast_tanh(dv * a0 + bias[bb + f4 + 0]);
            const float o1 = fast_tanh(dv * a1 + bias[bb + f4 + 1]);
            const float o2 = fast_tanh(dv * a2 + bias[bb + f4 + 2]);
            const float o3 = fast_tanh(dv * a3 + bias[bb + f4 + 3]);
            *(float4*)(hcur + d * 36 + f4) = make_float4(o0, o1, o2, o3);
            if (archOff >= 0) {
                const __half2 p01 = __floats2half2_rn(o0, o1);
                const __half2 p23 = __floats2half2_rn(o2, o3);
                __half2* dst = (__half2*)(arch + (size_t)(gbase + d) * 64 + archOff + f4);
                dst[0] = p01;
                dst[1] = p23;
            }
        }
    };

    auto gemm_mid = [&](const float* __restrict__ src) {
        // bufX = (src[200x32] @ W[32x32]) scaled by dinv[row]; W staged in wreg.
        const int f = f32lane;
        #pragma unroll
        for (int j0 = 0; j0 < 12; j0 += 4) {
            const int r0 = islot + 16 * j0;
            float a0 = 0.f, a1 = 0.f, a2 = 0.f, a3 = 0.f;
            #pragma unroll 2
            for (int k4 = 0; k4 < 8; ++k4) {
                const float w0 = wreg[k4 * 128 + 0  + f];
                const float w1 = wreg[k4 * 128 + 32 + f];
                const float w2 = wreg[k4 * 128 + 64 + f];
                const float w3 = wreg[k4 * 128 + 96 + f];
                float4 v;
                v = *(const float4*)(src + (r0      ) * 36 + k4 * 4); a0 += v.x*w0 + v.y*w1 + v.z*w2 + v.w*w3;
                v = *(const float4*)(src + (r0 + 16 ) * 36 + k4 * 4); a1 += v.x*w0 + v.y*w1 + v.z*w2 + v.w*w3;
                v = *(const float4*)(src + (r0 + 32 ) * 36 + k4 * 4); a2 += v.x*w0 + v.y*w1 + v.z*w2 + v.w*w3;
                v = *(const float4*)(src + (r0 + 48 ) * 36 + k4 * 4); a3 += v.x*w0 + v.y*w1 + v.z*w2 + v.w*w3;
            }
            bufX[(r0      ) * 36 + f] = dinv[r0      ] * a0;
            bufX[(r0 + 16 ) * 36 + f] = dinv[r0 + 16 ] * a1;
            bufX[(r0 + 32 ) * 36 + f] = dinv[r0 + 32 ] * a2;
            bufX[(r0 + 48 ) * 36 + f] = dinv[r0 + 48 ] * a3;
        }
        if (islot < 8) {   // rows 192..199
            const int r = 192 + islot;
            float a0 = 0.f;
            #pragma unroll 2
            for (int k4 = 0; k4 < 8; ++k4) {
                const float w0 = wreg[k4 * 128 + 0  + f];
                const float w1 = wreg[k4 * 128 + 32 + f];
                const float w2 = wreg[k4 * 128 + 64 + f];
                const float w3 = wreg[k4 * 128 + 96 + f];
                const float4 v = *(const float4*)(src + r * 36 + k4 * 4);
                a0 += v.x*w0 + v.y*w1 + v.z*w2 + v.w*w3;
            }
            bufX[r * 36 + f] = dinv[r] * a0;
        }
    };

    // ---------------- Layer 1 agg (+ stage W2/b2 in-phase, bias double-buffer) --------
    agg_layer(0, 0);    // h1 -> arch[:,0:32)
    for (int idx = t; idx < 1024; idx += TPB) wreg[idx] = W2[idx];
    if (t < 32) bias[32 + t] = b2[t];
    __syncthreads();

    // ---------------- Layer 2 ----------------
    gemm_mid(hcur);
    __syncthreads();
    agg_layer(32, 32);  // h2 -> arch[:,32:64)
    for (int idx = t; idx < 1024; idx += TPB) wreg[idx] = W3[idx];
    if (t < 32) bias[t] = b3[t];
    __syncthreads();

    // ---------------- Layer 3 ----------------
    gemm_mid(hcur);
    __syncthreads();
    agg_layer(-1, 0);   // h3 stays in hcur (f32), not archived
    __syncthreads();

    // ---------------- Layer 4 (Fout=1): scl = dinv * (h3 @ W4); scl[200]=0 ----------------
    float* scl = (float*)(smem + OFF_CNT);   // 400 floats available (cnt+cur dead)
    if (t < MG) {
        float a = 0.f;
        #pragma unroll 8
        for (int k = 0; k < 32; ++k) a += hcur[t * 36 + k] * W4[k];
        scl[t] = dinv[t] * a;
    }
    if (t == 200) scl[200] = 0.f;
    __syncthreads();
    if (t < MG) {
        const int p0 = roff[t], p1 = roff[t + 1];
        float s = 0.f;
        for (int p = p0; p < p1; p += 4) {
            const unsigned q = *(const unsigned*)(csr + p);
            s += scl[q & 255u] + scl[(q >> 8) & 255u]
               + scl[(q >> 16) & 255u] + scl[q >> 24];
        }
        h4k[t] = fast_tanh(dinv[t] * s + b4[0]);
    }
    __syncthreads();

    // ---------------- SortPool: exact stable rank (desc value, asc index) ----------------
    {
        const int i = t & 255;
        const int half = t >> 8;   // 0 or 1
        if (i < MG) {
            const float vi = h4k[i];
            int r = 0;
            const int j0 = half * 100, j1 = half * 100 + 100;
            for (int j = j0; j < j1; ++j) {
                const float vj = h4k[j];
                r += (vj > vi || (vj == vi && j < i)) ? 1 : 0;
            }
            atomicAdd(&rank[i], r);
        }
    }
    __syncthreads();
    if (t < MG) {
        const int r = rank[t];
        if (r < 30) ord[r] = t;
    }
    __syncthreads();

    // ---------------- Stage conv weights (bufX tail) + gather top-30 features ----------
    float* topv = bufX;           // [30][100] = 3000 floats
    float* cw   = bufX + 3104;    // cW1: [0,1552)  cW2: [1552,4112); ends at 7216 <= 7236
    for (int idx = t; idx < 1552; idx += TPB) cw[idx] = cW1[idx];
    for (int idx = t; idx < 2560; idx += TPB) cw[1552 + idx] = cW2[idx];
    if (t < 16) bias[t] = cb1[t];
    else if (t < 48) bias[t] = cb2[t - 16];
    for (int idx = t; idx < 2910; idx += TPB) {   // 30*97 grid-stride
        const int kk = idx / 97;
        const int ff = idx - kk * 97;
        const int nd = ord[kk];
        float v;
        if      (ff < 64) v = __half2float(arch[(size_t)(gbase + nd) * 64 + ff]);
        else if (ff < 96) v = hcur[nd * 36 + (ff - 64)];   // h3, f32
        else              v = h4k[nd];
        topv[kk * 100 + ff] = v;
    }
    __syncthreads();

    // conv scratch in hcur (dead after gather barrier)
    float* c1p2 = hcur;           // [16][30]
    float* c1pl = hcur + 480;     // [16][16]
    float* flat = hcur + 736;     // [352]
    float* hlin = hcur + 1088;    // [128]

    // ---------------- Conv1 (97->16 per slot) + ReLU ----------------
    if (t < 480) {
        const int o  = t & 15;
        const int tt = t >> 4;
        float a = bias[o];
        const float* wrow = cw + o * 97;
        const float* trow = topv + tt * 100;
        #pragma unroll 4
        for (int f = 0; f < 97; ++f) a += wrow[f] * trow[f];
        c1p2[o * 30 + tt] = fmaxf(a, 0.f);
    }
    __syncthreads();

    // ---------------- MaxPool1d(2,2): 30 -> 15 ----------------
    if (t < 240) {
        const int o  = t & 15;
        const int tp = t >> 4;
        c1pl[o * 16 + tp] = fmaxf(c1p2[o * 30 + 2 * tp], c1p2[o * 30 + 2 * tp + 1]);
    }
    __syncthreads();

    // ---------------- Conv2 (16->32, k=5) + ReLU -> flat; init hlin ----------------
    if (t < 352) {
        const int o  = t & 31;
        const int tt = t >> 5;
        float a = bias[16 + o];
        const float* w2r = cw + 1552 + o * 80;
        #pragma unroll
        for (int i2 = 0; i2 < 16; ++i2) {
            #pragma unroll
            for (int kk = 0; kk < 5; ++kk)
                a += w2r[i2 * 5 + kk] * c1pl[i2 * 16 + tt + kk];
        }
        flat[o * 11 + tt] = fmaxf(a, 0.f);
    } else if (t >= 352 && t < 480) {
        hlin[t - 352] = lb1[t - 352];
    }
    __syncthreads();

    // ---------------- Linear 352->128 (split-K over 4 groups of 88) ----------------
    {
        const int f  = t & 127;
        const int kc = t >> 7;   // 0..3
        float a = 0.f;
        const int k0 = kc * 88;
        #pragma unroll 4
        for (int kk = k0; kk < k0 + 88; ++kk) a += flat[kk] * lW1[kk * 128 + f];
        atomicAdd(&hlin[f], a);
    }
    __syncthreads();

    // ---------------- ReLU -> Linear 128->1 -> sigmoid ----------------
    if (t < 128) {
        float p = fmaxf(hlin[t], 0.f) * lW2[t];
        #pragma unroll
        for (int off = 32; off > 0; off >>= 1) p += __shfl_down(p, off);
        if ((t & 63) == 0) red[t >> 6] = p;
    }
    __syncthreads();
    if (t == 0) {
        const float z = red[0] + red[1] + lb2[0];
        out[g] = 1.f / (1.f + expf(-z));
    }
}

extern "C" void kernel_launch(void* const* d_in, const int* in_sizes, int n_in,
                              void* d_out, int out_size, void* d_ws, size_t ws_size,
                              hipStream_t stream) {
    (void)in_sizes; (void)n_in; (void)out_size; (void)ws_size;
    const float* x   = (const float*)d_in[0];
    const int*   ei  = (const int*)d_in[1];
    const float* W1  = (const float*)d_in[3];  const float* b1  = (const float*)d_in[4];
    const float* W2  = (const float*)d_in[5];  const float* b2  = (const float*)d_in[6];
    const float* W3  = (const float*)d_in[7];  const float* b3  = (const float*)d_in[8];
    const float* W4  = (const float*)d_in[9];  const float* b4  = (const float*)d_in[10];
    const float* cW1 = (const float*)d_in[11]; const float* cb1 = (const float*)d_in[12];
    const float* cW2 = (const float*)d_in[13]; const float* cb2 = (const float*)d_in[14];
    const float* lW1 = (const float*)d_in[15]; const float* lb1 = (const float*)d_in[16];
    const float* lW2 = (const float*)d_in[17]; const float* lb2 = (const float*)d_in[18];
    float* out = (float*)d_out;
    __half* arch = (__half*)d_ws;   // needs 512*200*64*2 = 13.1 MB

    hipFuncSetAttribute((const void*)dgcnn_kernel,
                        hipFuncAttributeMaxDynamicSharedMemorySize, SMEM_BYTES);

    dgcnn_kernel<<<GRID, TPB, SMEM_BYTES, stream>>>(
        x, ei, W1, b1, W2, b2, W3, b3, W4, b4,
        cW1, cb1, cW2, cb2, lW1, lb1, lW2, lb2, arch, out);
}

// Round 10
// 259.159 us; speedup vs baseline: 1.1094x; 1.0223x over previous
//
#include <hip/hip_runtime.h>
#include <hip/hip_fp16.h>

// DGCNN forward, fully fused: one workgroup per graph, TPB=512 (8 waves),
// 2 blocks/CU co-resident. f32 on the entire sort-key chain; h1/h2 archived
// to global f16 (conv features only); h3 read back from LDS f32.
//
// Occupancy rules learned R3-R9 (MI355X):
//  * NO launch_bounds min-waves / waves_per_eu hints -> allocator over-shrinks
//    to 32 VGPR and spills ~200 MB/launch to scratch.
//  * 2 blocks x 8 waves co-schedule at VGPR<=64 (empirical ~256/SIMD pool);
//    keep VGPR under 64 at all costs, but never via attributes.
//  * Between-phase overlap is NOT the stall (R9 neutral); within-wave
//    dependency latency in agg + L1 GEMM is. R10: 2-row interleaved agg with
//    csr-quad prefetch (2 independent LDS chains/thread) + W1 staged in LDS.

#define TPB   512
#define GRID  512
#define MG    200
#define EPG   6400
#define EE    (512 * EPG)

// ---- LDS layout (byte offsets). Total 74,304 B -> 2 blocks/CU (148.6/160 KiB) ----
#define OFF_BUFX 0        // f32[201*36] rows 0..200 (row 200 = zeros); later topv[30][100] + conv W
#define OFF_HCUR 28944    // f32[200*36] h of current layer; Phase A/B: staged W1 (4096 f)
#define OFF_CSR  57744    // u8[7200]    CSR (rows padded to x4 entries, pad -> 200)
#define OFF_ROFF 64944    // i32[201] row offsets (padded units)
#define OFF_CNT  65760    // i32[200] degree counts   \ scl f32[201] aliases CNT..CUR
#define OFF_CUR  66560    // i32[200] cursors         /
#define OFF_DINV 67360    // f32[200]
#define OFF_H4   68160    // f32[200] sort key
#define OFF_RANK 68960    // i32[200]
#define OFF_ORD  69760    // i32[30]
#define OFF_BIAS 69880    // f32[64]  double-buffered layer bias
#define OFF_RED  70136    // f32[16] (+8 pad)
#define OFF_WREG 70208    // f32[1024] W2/W3 stage
#define SMEM_BYTES 74304

#define QPAD 0xC8C8C8C8u   // 4x index 200 (zero row) - exact no-op quad

__device__ __forceinline__ float fast_tanh(float x) {
    const float e = __expf(2.0f * x);
    return 1.0f - 2.0f / (e + 1.0f);
}

__global__ __launch_bounds__(TPB)
void dgcnn_kernel(
    const float* __restrict__ x,
    const int*   __restrict__ ei,
    const float* __restrict__ W1, const float* __restrict__ b1,
    const float* __restrict__ W2, const float* __restrict__ b2,
    const float* __restrict__ W3, const float* __restrict__ b3,
    const float* __restrict__ W4, const float* __restrict__ b4,
    const float* __restrict__ cW1, const float* __restrict__ cb1,
    const float* __restrict__ cW2, const float* __restrict__ cb2,
    const float* __restrict__ lW1, const float* __restrict__ lb1,
    const float* __restrict__ lW2, const float* __restrict__ lb2,
    __half* __restrict__ arch,     // [512][200][64] f16 archive of h1|h2
    float* __restrict__ out)
{
    extern __shared__ unsigned char smem[];
    float* bufX = (float*)(smem + OFF_BUFX);
    float* hcur = (float*)(smem + OFF_HCUR);
    unsigned char* csr = (unsigned char*)(smem + OFF_CSR);
    int*   roff = (int*)(smem + OFF_ROFF);
    int*   cnt  = (int*)(smem + OFF_CNT);
    int*   cur  = (int*)(smem + OFF_CUR);
    float* dinv = (float*)(smem + OFF_DINV);
    float* h4k  = (float*)(smem + OFF_H4);
    int*   rank = (int*)(smem + OFF_RANK);
    int*   ord  = (int*)(smem + OFF_ORD);
    float* bias = (float*)(smem + OFF_BIAS);
    float* red  = (float*)(smem + OFF_RED);
    float* wreg = (float*)(smem + OFF_WREG);

    const int g = blockIdx.x;
    const int t = threadIdx.x;
    const int gbase = g * MG;
    const float* xg   = x + (size_t)gbase * 128;
    const int*   srcp = ei + (size_t)g * EPG;
    const int*   dstp = ei + (size_t)EE + (size_t)g * EPG;

    // ---------------- Phase A: stage W1 -> hcur (dead until agg-1), bias, zeros -----------
    for (int idx = t; idx < 4096; idx += TPB) hcur[idx] = W1[idx];
    if (t < 32) bias[t] = b1[t];
    if (t < MG) { cnt[t] = 0; rank[t] = 0; }
    if (t >= 256 && t < 292) bufX[200 * 36 + (t - 256)] = 0.f;   // zero row 200
    __syncthreads();

    const int f32lane = t & 31;   // feature (output col) 0..31
    const int islot   = t >> 5;   // row slot 0..15

    // ---------------- Phase B: edge in-degree count (int4) + L1 GEMM, one phase ----------
    // Independent work co-scheduled; GEMM writes UNSCALED xw (dinv applied in
    // Phase D - identical arithmetic). W1 read from LDS (hcur), x broadcast from L1$.
    {
        const int4* d4p = (const int4*)dstp;
        for (int e4 = t; e4 < EPG / 4; e4 += TPB) {
            const int4 d4 = d4p[e4];
            atomicAdd(&cnt[d4.x - gbase], 1);
            atomicAdd(&cnt[d4.y - gbase], 1);
            atomicAdd(&cnt[d4.z - gbase], 1);
            atomicAdd(&cnt[d4.w - gbase], 1);
        }
    }
    {
        const int f = f32lane;
        const float* wr1 = hcur;
        const float4* xv = (const float4*)xg;
        #pragma unroll
        for (int j0 = 0; j0 < 12; j0 += 4) {
            const int r0 = islot + 16 * j0;
            float a0 = 0.f, a1 = 0.f, a2 = 0.f, a3 = 0.f;
            #pragma unroll 2
            for (int k4 = 0; k4 < 32; ++k4) {
                const float w0 = wr1[k4 * 128 + 0  + f];
                const float w1 = wr1[k4 * 128 + 32 + f];
                const float w2 = wr1[k4 * 128 + 64 + f];
                const float w3 = wr1[k4 * 128 + 96 + f];
                float4 v;
                v = xv[(r0      ) * 32 + k4]; a0 += v.x*w0 + v.y*w1 + v.z*w2 + v.w*w3;
                v = xv[(r0 + 16 ) * 32 + k4]; a1 += v.x*w0 + v.y*w1 + v.z*w2 + v.w*w3;
                v = xv[(r0 + 32 ) * 32 + k4]; a2 += v.x*w0 + v.y*w1 + v.z*w2 + v.w*w3;
                v = xv[(r0 + 48 ) * 32 + k4]; a3 += v.x*w0 + v.y*w1 + v.z*w2 + v.w*w3;
            }
            bufX[(r0      ) * 36 + f] = a0;
            bufX[(r0 + 16 ) * 36 + f] = a1;
            bufX[(r0 + 32 ) * 36 + f] = a2;
            bufX[(r0 + 48 ) * 36 + f] = a3;
        }
        if (islot < 8) {   // rows 192..199
            const int r = 192 + islot;
            float a0 = 0.f;
            #pragma unroll 2
            for (int k4 = 0; k4 < 32; ++k4) {
                const float w0 = wr1[k4 * 128 + 0  + f];
                const float w1 = wr1[k4 * 128 + 32 + f];
                const float w2 = wr1[k4 * 128 + 64 + f];
                const float w3 = wr1[k4 * 128 + 96 + f];
                const float4 v = xv[r * 32 + k4];
                a0 += v.x*w0 + v.y*w1 + v.z*w2 + v.w*w3;
            }
            bufX[r * 36 + f] = a0;
        }
    }
    __syncthreads();

    // ---------------- Phase C: dinv + prefix scan over PADDED row lengths ----------------
    if (t >= 256 && t < 256 + MG) {
        int i = t - 256;
        dinv[i] = 1.0f / sqrtf((float)(cnt[i] + 1));
    }
    if (t < 64) {
        if (t == 0) roff[0] = 0;
        int carry = 0;
        #pragma unroll
        for (int c = 0; c < 4; ++c) {
            const int i = c * 64 + t;
            int v = (i < MG) ? ((cnt[i] + 4) & ~3) : 0;   // self-loop +1, pad to x4
            #pragma unroll
            for (int off = 1; off < 64; off <<= 1) {
                int u = __shfl_up(v, off);
                if (t >= (int)off) v += u;
            }
            if (i < MG) roff[i + 1] = carry + v;
            carry += __shfl(v, 63);
        }
    }
    __syncthreads();

    // ---------------- Phase D: self-loop entry + cursors + dinv-scale bufX ----------------
    if (t < MG) {
        int p = roff[t];
        csr[p] = (unsigned char)t;
        cur[t] = p + 1;
    }
    for (int r = islot; r < MG; r += 16) {
        bufX[r * 36 + f32lane] *= dinv[r];
    }
    __syncthreads();

    // ---------------- Phase E: CSR placement (int4 edge loads) ----------------
    {
        const int4* s4p = (const int4*)srcp;
        const int4* d4p = (const int4*)dstp;
        for (int e4 = t; e4 < EPG / 4; e4 += TPB) {
            const int4 s4 = s4p[e4];
            const int4 d4 = d4p[e4];
            int p;
            p = atomicAdd(&cur[d4.x - gbase], 1); csr[p] = (unsigned char)(s4.x - gbase);
            p = atomicAdd(&cur[d4.y - gbase], 1); csr[p] = (unsigned char)(s4.y - gbase);
            p = atomicAdd(&cur[d4.z - gbase], 1); csr[p] = (unsigned char)(s4.z - gbase);
            p = atomicAdd(&cur[d4.w - gbase], 1); csr[p] = (unsigned char)(s4.w - gbase);
        }
    }
    __syncthreads();

    // ---------------- Phase F: fill padding slots with zero-row index 200 ----------------
    if (t < MG) {
        for (int p = cur[t]; p < roff[t + 1]; ++p) csr[p] = (unsigned char)200;
    }
    __syncthreads();

    // agg: hcur[d][f] = tanh(dinv[d]*sum_{p} bufX[csr[p]][f] + bias[bb+f]);
    // 2-row interleaved + csr-quad prefetch. Short rows pad with QPAD (row 200,
    // zeros) -> exact. archOff >= 0: archive to global f16 at column archOff.
    auto agg_layer = [&](int archOff, int bb) {
        const int f4  = (t & 7) << 2;
        const int dsl = t >> 3;   // 0..63

        auto finish = [&](int d, float a0, float a1, float a2, float a3) {
            const float dv = dinv[d];
            const float o0 = fast_tanh(dv * a0 + bias[bb + f4 + 0]);
            const float o1 = fast_tanh(dv * a1 + bias[bb + f4 + 1]);
            const float o2 = fast_tanh(dv * a2 + bias[bb + f4 + 2]);
            const float o3 = fast_tanh(dv * a3 + bias[bb + f4 + 3]);
            *(float4*)(hcur + d * 36 + f4) = make_float4(o0, o1, o2, o3);
            if (archOff >= 0) {
                const __half2 p01 = __floats2half2_rn(o0, o1);
                const __half2 p23 = __floats2half2_rn(o2, o3);
                __half2* dst = (__half2*)(arch + (size_t)(gbase + d) * 64 + archOff + f4);
                dst[0] = p01;
                dst[1] = p23;
            }
        };

        auto pair_rows = [&](int da, int db) {
            const int p1a = roff[da + 1], p1b = roff[db + 1];
            int pa = roff[da], pb = roff[db];
            const int na = (p1a - pa) >> 2, nb = (p1b - pb) >> 2;
            const int iters = na > nb ? na : nb;
            unsigned qa = *(const unsigned*)(csr + pa);
            unsigned qb = *(const unsigned*)(csr + pb);
            float a0=0.f,a1=0.f,a2=0.f,a3=0.f, c0=0.f,c1=0.f,c2=0.f,c3=0.f;
            for (int i = 0; i < iters; ++i) {
                pa += 4; pb += 4;
                const unsigned qa_n = (pa < p1a) ? *(const unsigned*)(csr + pa) : QPAD;
                const unsigned qb_n = (pb < p1b) ? *(const unsigned*)(csr + pb) : QPAD;
                float4 v;
                v = *(const float4*)(bufX + (qa & 255u) * 36 + f4);         a0+=v.x; a1+=v.y; a2+=v.z; a3+=v.w;
                v = *(const float4*)(bufX + ((qa >> 8) & 255u) * 36 + f4);  a0+=v.x; a1+=v.y; a2+=v.z; a3+=v.w;
                v = *(const float4*)(bufX + ((qa >> 16) & 255u) * 36 + f4); a0+=v.x; a1+=v.y; a2+=v.z; a3+=v.w;
                v = *(const float4*)(bufX + (qa >> 24) * 36 + f4);          a0+=v.x; a1+=v.y; a2+=v.z; a3+=v.w;
                v = *(const float4*)(bufX + (qb & 255u) * 36 + f4);         c0+=v.x; c1+=v.y; c2+=v.z; c3+=v.w;
                v = *(const float4*)(bufX + ((qb >> 8) & 255u) * 36 + f4);  c0+=v.x; c1+=v.y; c2+=v.z; c3+=v.w;
                v = *(const float4*)(bufX + ((qb >> 16) & 255u) * 36 + f4); c0+=v.x; c1+=v.y; c2+=v.z; c3+=v.w;
                v = *(const float4*)(bufX + (qb >> 24) * 36 + f4);          c0+=v.x; c1+=v.y; c2+=v.z; c3+=v.w;
                qa = qa_n; qb = qb_n;
            }
            finish(da, a0, a1, a2, a3);
            finish(db, c0, c1, c2, c3);
        };

        auto one_row = [&](int d) {
            const int p1 = roff[d + 1];
            int p = roff[d];
            const int iters = (p1 - p) >> 2;
            unsigned q = *(const unsigned*)(csr + p);
            float a0=0.f,a1=0.f,a2=0.f,a3=0.f;
            for (int i = 0; i < iters; ++i) {
                p += 4;
                const unsigned q_n = (p < p1) ? *(const unsigned*)(csr + p) : QPAD;
                float4 v;
                v = *(const float4*)(bufX + (q & 255u) * 36 + f4);         a0+=v.x; a1+=v.y; a2+=v.z; a3+=v.w;
                v = *(const float4*)(bufX + ((q >> 8) & 255u) * 36 + f4);  a0+=v.x; a1+=v.y; a2+=v.z; a3+=v.w;
                v = *(const float4*)(bufX + ((q >> 16) & 255u) * 36 + f4); a0+=v.x; a1+=v.y; a2+=v.z; a3+=v.w;
                v = *(const float4*)(bufX + (q >> 24) * 36 + f4);          a0+=v.x; a1+=v.y; a2+=v.z; a3+=v.w;
                q = q_n;
            }
            finish(d, a0, a1, a2, a3);
        };

        // Pass 1: rows dsl, dsl+64 (always both < 200)
        pair_rows(dsl, dsl + 64);
        // Pass 2: rows dsl+128 (all dsl) and dsl+192 (dsl<8).
        // Wave 0 (dsl 0..7) takes pair path; waves 1..7 single -> no intra-wave divergence.
        if (dsl < 8) pair_rows(dsl + 128, dsl + 192);
        else         one_row(dsl + 128);
    };

    auto gemm_mid = [&](const float* __restrict__ src) {
        // bufX = (src[200x32] @ W[32x32]) scaled by dinv[row]; W staged in wreg.
        const int f = f32lane;
        #pragma unroll
        for (int j0 = 0; j0 < 12; j0 += 4) {
            const int r0 = islot + 16 * j0;
            float a0 = 0.f, a1 = 0.f, a2 = 0.f, a3 = 0.f;
            #pragma unroll 2
            for (int k4 = 0; k4 < 8; ++k4) {
                const float w0 = wreg[k4 * 128 + 0  + f];
                const float w1 = wreg[k4 * 128 + 32 + f];
                const float w2 = wreg[k4 * 128 + 64 + f];
                const float w3 = wreg[k4 * 128 + 96 + f];
                float4 v;
                v = *(const float4*)(src + (r0      ) * 36 + k4 * 4); a0 += v.x*w0 + v.y*w1 + v.z*w2 + v.w*w3;
                v = *(const float4*)(src + (r0 + 16 ) * 36 + k4 * 4); a1 += v.x*w0 + v.y*w1 + v.z*w2 + v.w*w3;
                v = *(const float4*)(src + (r0 + 32 ) * 36 + k4 * 4); a2 += v.x*w0 + v.y*w1 + v.z*w2 + v.w*w3;
                v = *(const float4*)(src + (r0 + 48 ) * 36 + k4 * 4); a3 += v.x*w0 + v.y*w1 + v.z*w2 + v.w*w3;
            }
            bufX[(r0      ) * 36 + f] = dinv[r0      ] * a0;
            bufX[(r0 + 16 ) * 36 + f] = dinv[r0 + 16 ] * a1;
            bufX[(r0 + 32 ) * 36 + f] = dinv[r0 + 32 ] * a2;
            bufX[(r0 + 48 ) * 36 + f] = dinv[r0 + 48 ] * a3;
        }
        if (islot < 8) {   // rows 192..199
            const int r = 192 + islot;
            float a0 = 0.f;
            #pragma unroll 2
            for (int k4 = 0; k4 < 8; ++k4) {
                const float w0 = wreg[k4 * 128 + 0  + f];
                const float w1 = wreg[k4 * 128 + 32 + f];
                const float w2 = wreg[k4 * 128 + 64 + f];
                const float w3 = wreg[k4 * 128 + 96 + f];
                const float4 v = *(const float4*)(src + r * 36 + k4 * 4);
                a0 += v.x*w0 + v.y*w1 + v.z*w2 + v.w*w3;
            }
            bufX[r * 36 + f] = dinv[r] * a0;
        }
    };

    // ---------------- Layer 1 agg (+ stage W2/b2 in-phase, bias double-buffer) --------
    agg_layer(0, 0);    // h1 -> arch[:,0:32)
    for (int idx = t; idx < 1024; idx += TPB) wreg[idx] = W2[idx];
    if (t < 32) bias[32 + t] = b2[t];
    __syncthreads();

    // ---------------- Layer 2 ----------------
    gemm_mid(hcur);
    __syncthreads();
    agg_layer(32, 32);  // h2 -> arch[:,32:64)
    for (int idx = t; idx < 1024; idx += TPB) wreg[idx] = W3[idx];
    if (t < 32) bias[t] = b3[t];
    __syncthreads();

    // ---------------- Layer 3 ----------------
    gemm_mid(hcur);
    __syncthreads();
    agg_layer(-1, 0);   // h3 stays in hcur (f32), not archived
    __syncthreads();

    // ---------------- Layer 4 (Fout=1): scl = dinv * (h3 @ W4); scl[200]=0 ----------------
    float* scl = (float*)(smem + OFF_CNT);   // 400 floats available (cnt+cur dead)
    if (t < MG) {
        float a = 0.f;
        #pragma unroll 8
        for (int k = 0; k < 32; ++k) a += hcur[t * 36 + k] * W4[k];
        scl[t] = dinv[t] * a;
    }
    if (t == 200) scl[200] = 0.f;
    __syncthreads();
    if (t < MG) {
        const int p0 = roff[t], p1 = roff[t + 1];
        float s = 0.f;
        for (int p = p0; p < p1; p += 4) {
            const unsigned q = *(const unsigned*)(csr + p);
            s += scl[q & 255u] + scl[(q >> 8) & 255u]
               + scl[(q >> 16) & 255u] + scl[q >> 24];
        }
        h4k[t] = fast_tanh(dinv[t] * s + b4[0]);
    }
    __syncthreads();

    // ---------------- SortPool: exact stable rank (desc value, asc index) ----------------
    {
        const int i = t & 255;
        const int half = t >> 8;   // 0 or 1
        if (i < MG) {
            const float vi = h4k[i];
            int r = 0;
            const int j0 = half * 100, j1 = half * 100 + 100;
            for (int j = j0; j < j1; ++j) {
                const float vj = h4k[j];
                r += (vj > vi || (vj == vi && j < i)) ? 1 : 0;
            }
            atomicAdd(&rank[i], r);
        }
    }
    __syncthreads();
    if (t < MG) {
        const int r = rank[t];
        if (r < 30) ord[r] = t;
    }
    __syncthreads();

    // ---------------- Stage conv weights (bufX tail) + gather top-30 features ----------
    float* topv = bufX;           // [30][100] = 3000 floats
    float* cw   = bufX + 3104;    // cW1: [0,1552)  cW2: [1552,4112); ends at 7216 <= 7236
    for (int idx = t; idx < 1552; idx += TPB) cw[idx] = cW1[idx];
    for (int idx = t; idx < 2560; idx += TPB) cw[1552 + idx] = cW2[idx];
    if (t < 16) bias[t] = cb1[t];
    else if (t < 48) bias[t] = cb2[t - 16];
    for (int idx = t; idx < 2910; idx += TPB) {   // 30*97 grid-stride
        const int kk = idx / 97;
        const int ff = idx - kk * 97;
        const int nd = ord[kk];
        float v;
        if      (ff < 64) v = __half2float(arch[(size_t)(gbase + nd) * 64 + ff]);
        else if (ff < 96) v = hcur[nd * 36 + (ff - 64)];   // h3, f32
        else              v = h4k[nd];
        topv[kk * 100 + ff] = v;
    }
    __syncthreads();

    // conv scratch in hcur (dead after gather barrier)
    float* c1p2 = hcur;           // [16][30]
    float* c1pl = hcur + 480;     // [16][16]
    float* flat = hcur + 736;     // [352]
    float* hlin = hcur + 1088;    // [128]

    // ---------------- Conv1 (97->16 per slot) + ReLU ----------------
    if (t < 480) {
        const int o  = t & 15;
        const int tt = t >> 4;
        float a = bias[o];
        const float* wrow = cw + o * 97;
        const float* trow = topv + tt * 100;
        #pragma unroll 4
        for (int f = 0; f < 97; ++f) a += wrow[f] * trow[f];
        c1p2[o * 30 + tt] = fmaxf(a, 0.f);
    }
    __syncthreads();

    // ---------------- MaxPool1d(2,2): 30 -> 15 ----------------
    if (t < 240) {
        const int o  = t & 15;
        const int tp = t >> 4;
        c1pl[o * 16 + tp] = fmaxf(c1p2[o * 30 + 2 * tp], c1p2[o * 30 + 2 * tp + 1]);
    }
    __syncthreads();

    // ---------------- Conv2 (16->32, k=5) + ReLU -> flat; init hlin ----------------
    if (t < 352) {
        const int o  = t & 31;
        const int tt = t >> 5;
        float a = bias[16 + o];
        const float* w2r = cw + 1552 + o * 80;
        #pragma unroll
        for (int i2 = 0; i2 < 16; ++i2) {
            #pragma unroll
            for (int kk = 0; kk < 5; ++kk)
                a += w2r[i2 * 5 + kk] * c1pl[i2 * 16 + tt + kk];
        }
        flat[o * 11 + tt] = fmaxf(a, 0.f);
    } else if (t >= 352 && t < 480) {
        hlin[t - 352] = lb1[t - 352];
    }
    __syncthreads();

    // ---------------- Linear 352->128 (split-K over 4 groups of 88) ----------------
    {
        const int f  = t & 127;
        const int kc = t >> 7;   // 0..3
        float a = 0.f;
        const int k0 = kc * 88;
        #pragma unroll 4
        for (int kk = k0; kk < k0 + 88; ++kk) a += flat[kk] * lW1[kk * 128 + f];
        atomicAdd(&hlin[f], a);
    }
    __syncthreads();

    // ---------------- ReLU -> Linear 128->1 -> sigmoid ----------------
    if (t < 128) {
        float p = fmaxf(hlin[t], 0.f) * lW2[t];
        #pragma unroll
        for (int off = 32; off > 0; off >>= 1) p += __shfl_down(p, off);
        if ((t & 63) == 0) red[t >> 6] = p;
    }
    __syncthreads();
    if (t == 0) {
        const float z = red[0] + red[1] + lb2[0];
        out[g] = 1.f / (1.f + expf(-z));
    }
}

extern "C" void kernel_launch(void* const* d_in, const int* in_sizes, int n_in,
                              void* d_out, int out_size, void* d_ws, size_t ws_size,
                              hipStream_t stream) {
    (void)in_sizes; (void)n_in; (void)out_size; (void)ws_size;
    const float* x   = (const float*)d_in[0];
    const int*   ei  = (const int*)d_in[1];
    const float* W1  = (const float*)d_in[3];  const float* b1  = (const float*)d_in[4];
    const float* W2  = (const float*)d_in[5];  const float* b2  = (const float*)d_in[6];
    const float* W3  = (const float*)d_in[7];  const float* b3  = (const float*)d_in[8];
    const float* W4  = (const float*)d_in[9];  const float* b4  = (const float*)d_in[10];
    const float* cW1 = (const float*)d_in[11]; const float* cb1 = (const float*)d_in[12];
    const float* cW2 = (const float*)d_in[13]; const float* cb2 = (const float*)d_in[14];
    const float* lW1 = (const float*)d_in[15]; const float* lb1 = (const float*)d_in[16];
    const float* lW2 = (const float*)d_in[17]; const float* lb2 = (const float*)d_in[18];
    float* out = (float*)d_out;
    __half* arch = (__half*)d_ws;   // needs 512*200*64*2 = 13.1 MB

    hipFuncSetAttribute((const void*)dgcnn_kernel,
                        hipFuncAttributeMaxDynamicSharedMemorySize, SMEM_BYTES);

    dgcnn_kernel<<<GRID, TPB, SMEM_BYTES, stream>>>(
        x, ei, W1, b1, W2, b2, W3, b3, W4, b4,
        cW1, cb1, cW2, cb2, lW1, lb1, lW2, lb2, arch, out);
}